// Round 1
// baseline (1138.062 us; speedup 1.0000x reference)
//
#include <hip/hip_runtime.h>

#define BB   256
#define TT   512
#define EMBD 64
#define CHARD 50
#define DIN  114
#define RNN  128
#define NG   512   // 4*RNN
#define TAGS 9

typedef __bf16 bf16x8 __attribute__((ext_vector_type(8)));
typedef float  f32x4  __attribute__((ext_vector_type(4)));

static __device__ __forceinline__ unsigned short f2bf(float f) {
  unsigned int u = __float_as_uint(f);
  unsigned int r = (u + 0x7FFFu + ((u >> 16) & 1u)) >> 16;  // RNE
  return (unsigned short)r;
}
static __device__ __forceinline__ float bf2f(unsigned short s) {
  return __uint_as_float(((unsigned int)s) << 16);
}
static __device__ __forceinline__ float sigf(float x) { return 1.f / (1.f + __expf(-x)); }
static __device__ __forceinline__ float tanhfast(float x) {
  float ax = fabsf(x);
  float e  = __expf(2.f * ax);
  float t  = 1.f - 2.f / (e + 1.f);   // overflow-safe: e=inf -> t=1
  return copysignf(t, x);
}

// ---------------- x = concat(E[inputs], char_emb) padded to 128, bf16 ----------------
__global__ void k_build_x(const int* __restrict__ inp, const float* __restrict__ ch,
                          const float* __restrict__ E, unsigned short* __restrict__ x) {
  int idx = blockIdx.x * 256 + threadIdx.x;   // over B*T*128
  int k   = idx & 127;
  int row = idx >> 7;                          // b*T+t
  float v;
  if (k < EMBD)      v = E[inp[row] * EMBD + k];
  else if (k < DIN)  v = ch[row * CHARD + (k - EMBD)];
  else               v = 0.f;
  x[idx] = f2bf(v);
}

// ------------- transpose weights to [n][k] bf16 so B-fragments are contiguous -------------
__global__ void k_prep_w(const float* __restrict__ Wx_f, const float* __restrict__ Wh_f,
                         const float* __restrict__ Wx_b, const float* __restrict__ Wh_b,
                         unsigned short* __restrict__ WxT, unsigned short* __restrict__ WhT) {
  int idx = blockIdx.x * 256 + threadIdx.x;   // over 2*512*128
  int dir = idx >> 16;
  int rem = idx & 65535;
  int n   = rem >> 7;
  int kk  = rem & 127;
  const float* Wx = dir ? Wx_b : Wx_f;
  const float* Wh = dir ? Wh_b : Wh_f;
  WxT[idx] = (kk < DIN) ? f2bf(Wx[kk * NG + n]) : (unsigned short)0;
  WhT[idx] = f2bf(Wh[kk * NG + n]);
}

__global__ void k_lengths(const int* __restrict__ labels, int* __restrict__ lengths) {
  int b = blockIdx.x, lane = threadIdx.x;
  int cnt = 0;
  for (int t = lane; t < TT; t += 64) cnt += (labels[b * TT + t] != 0);
  for (int o = 32; o > 0; o >>= 1) cnt += __shfl_down(cnt, o);
  if (lane == 0) lengths[b] = cnt;
}

// ---------------- the sequential BiLSTM recurrence ----------------
// 32 WGs: wg<16 forward, wg>=16 backward; each WG owns 16 batch rows.
// Weights (Wx^T, Wh^T) live in registers as MFMA B-fragments (consistent slot
// mapping for A and B => layout-invariant correctness). h double-buffered in LDS,
// c persistent in VGPRs. One barrier per step.
__global__ __launch_bounds__(512, 2) void k_lstm(
    const unsigned short* __restrict__ x,     // [B][T][128] bf16
    const unsigned short* __restrict__ WxT,   // [2][512][128] bf16
    const unsigned short* __restrict__ WhT,   // [2][512][128] bf16
    const float* __restrict__ b_f, const float* __restrict__ b_b,
    unsigned short* __restrict__ hseq)        // [2][B][T][128] bf16
{
  int wg  = blockIdx.x;
  int dir = wg >> 4;
  int b0  = (wg & 15) * 16;
  int tid = threadIdx.x;
  int w   = tid >> 6;          // wave 0..7: owns hidden slice [w*16, w*16+16)
  int lane = tid & 63;
  int lq = lane & 15, lg = lane >> 4;

  const unsigned short* WxD = WxT + dir * (NG * 128);
  const unsigned short* WhD = WhT + dir * (NG * 128);
  const float* bias = dir ? b_b : b_f;
  unsigned short* hout = hseq + dir * (BB * TT * 128);

  // B-fragments: [gate][ktile]; n = gate*128 + w*16 + lq, k = ktile*32 + lg*8 ..+8
  bf16x8 wx[4][4], wh[4][4];
  float  bs[4];
  #pragma unroll
  for (int g = 0; g < 4; ++g) {
    int n = g * RNN + w * 16 + lq;
    bs[g] = bias[n];
    #pragma unroll
    for (int kt = 0; kt < 4; ++kt) {
      wx[g][kt] = *reinterpret_cast<const bf16x8*>(WxD + n * 128 + kt * 32 + lg * 8);
      wh[g][kt] = *reinterpret_cast<const bf16x8*>(WhD + n * 128 + kt * 32 + lg * 8);
    }
  }

  __shared__ __align__(16) unsigned short hbuf[2][16][136];  // rows padded: 272B stride
  for (int i = tid; i < 2 * 16 * 136; i += 512) (&hbuf[0][0][0])[i] = 0;

  f32x4 c = {0.f, 0.f, 0.f, 0.f};
  __syncthreads();

  // preload x fragments for step 0 (A-frag: m = lq = batch row, k = ktile*32+lg*8)
  int t0 = dir ? (TT - 1) : 0;
  const unsigned short* xr0 = x + ((b0 + lq) * TT + t0) * 128 + lg * 8;
  bf16x8 xf[4];
  #pragma unroll
  for (int kt = 0; kt < 4; ++kt) xf[kt] = *reinterpret_cast<const bf16x8*>(xr0 + kt * 32);

  for (int s = 0; s < TT; ++s) {
    int t = dir ? (TT - 1 - s) : s;

    // prefetch next step's x fragments (hides global latency under MFMA+gates)
    bf16x8 xn[4];
    int sn = (s + 1 < TT) ? (s + 1) : s;
    int tn = dir ? (TT - 1 - sn) : sn;
    const unsigned short* xrn = x + ((b0 + lq) * TT + tn) * 128 + lg * 8;
    #pragma unroll
    for (int kt = 0; kt < 4; ++kt) xn[kt] = *reinterpret_cast<const bf16x8*>(xrn + kt * 32);

    // h fragments from LDS (prev step)
    bf16x8 hf[4];
    const unsigned short* hrow = &hbuf[s & 1][lq][lg * 8];
    #pragma unroll
    for (int kt = 0; kt < 4; ++kt) hf[kt] = *reinterpret_cast<const bf16x8*>(hrow + kt * 32);

    f32x4 acc[4];
    #pragma unroll
    for (int g = 0; g < 4; ++g) acc[g] = f32x4{0.f, 0.f, 0.f, 0.f};
    #pragma unroll
    for (int kt = 0; kt < 4; ++kt)
      #pragma unroll
      for (int g = 0; g < 4; ++g) {
        acc[g] = __builtin_amdgcn_mfma_f32_16x16x32_bf16(xf[kt], wx[g][kt], acc[g], 0, 0, 0);
        acc[g] = __builtin_amdgcn_mfma_f32_16x16x32_bf16(hf[kt], wh[g][kt], acc[g], 0, 0, 0);
      }

    // gates; C/D layout: col = lq (hidden within slice), row = lg*4 + r (batch)
    unsigned short* hwr = &hbuf[(s + 1) & 1][0][0];
    #pragma unroll
    for (int r = 0; r < 4; ++r) {
      float zi = acc[0][r] + bs[0];
      float zf = acc[1][r] + bs[1];
      float zg = acc[2][r] + bs[2];
      float zo = acc[3][r] + bs[3];
      float cn = sigf(zf) * c[r] + sigf(zi) * tanhfast(zg);
      float hn = sigf(zo) * tanhfast(cn);
      c[r] = cn;
      unsigned short hb = f2bf(hn);
      int brow = lg * 4 + r;
      hwr[brow * 136 + w * 16 + lq] = hb;
      hout[((b0 + brow) * TT + t) * 128 + w * 16 + lq] = hb;
    }
    #pragma unroll
    for (int kt = 0; kt < 4; ++kt) xf[kt] = xn[kt];
    __syncthreads();
  }
}

// ---------------- logits = [h_f, h_b] @ Wd + bd ----------------
__global__ void k_logits(const unsigned short* __restrict__ hseq,
                         const float* __restrict__ Wd, const float* __restrict__ bd,
                         float* __restrict__ logits) {
  __shared__ __align__(16) float sW[2 * RNN * 12];  // rows padded 9->12 for float4 loads
  __shared__ float sb[TAGS];
  int tid = threadIdx.x;
  for (int i = tid; i < 2 * RNN * TAGS; i += 256) {
    int k = i / TAGS, j = i - k * TAGS;
    sW[k * 12 + j] = Wd[i];
  }
  if (tid < TAGS) sb[tid] = bd[tid];
  __syncthreads();

  int bt = blockIdx.x * 256 + tid;   // b*T + t
  float a[TAGS];
  #pragma unroll
  for (int j = 0; j < TAGS; ++j) a[j] = sb[j];

  const unsigned short* hp[2];
  hp[0] = hseq + (size_t)bt * 128;
  hp[1] = hseq + (size_t)BB * TT * 128 + (size_t)bt * 128;
  #pragma unroll
  for (int d = 0; d < 2; ++d) {
    #pragma unroll
    for (int kv = 0; kv < RNN / 8; ++kv) {
      bf16x8 v = *reinterpret_cast<const bf16x8*>(hp[d] + kv * 8);
      #pragma unroll
      for (int e = 0; e < 8; ++e) {
        float f = (float)v[e];
        int k = d * RNN + kv * 8 + e;
        const float4* wrow = reinterpret_cast<const float4*>(sW + k * 12);
        float4 wa = wrow[0], wb = wrow[1];
        float  wc = sW[k * 12 + 8];
        a[0] += f * wa.x; a[1] += f * wa.y; a[2] += f * wa.z; a[3] += f * wa.w;
        a[4] += f * wb.x; a[5] += f * wb.y; a[6] += f * wb.z; a[7] += f * wb.w;
        a[8] += f * wc;
      }
    }
  }
  #pragma unroll
  for (int j = 0; j < TAGS; ++j) logits[(size_t)bt * TAGS + j] = a[j];
}

// ---------------- CRF log-likelihood; one wave per batch row ----------------
__global__ void k_crf(const float* __restrict__ logits, const int* __restrict__ labels,
                      const int* __restrict__ lengths, const float* __restrict__ trans,
                      float* __restrict__ out) {
  int b = blockIdx.x;
  int lane = threadIdx.x;
  int len = lengths[b];
  const float* lg = logits + (size_t)b * TT * TAGS;
  const int*   lab = labels + b * TT;

  // unary + binary scores, lane-parallel over t
  float sc = 0.f;
  for (int t = lane; t < TT; t += 64) {
    if (t < len) {
      sc += lg[t * TAGS + lab[t]];
      if (t >= 1) sc += trans[lab[t - 1] * TAGS + lab[t]];
    }
  }
  for (int o = 32; o > 0; o >>= 1) sc += __shfl_down(sc, o);
  sc = __shfl(sc, 0);

  // forward algorithm: lane j owns tag j; alpha replicated across lanes
  int j = (lane < TAGS) ? lane : 0;
  float Tc[TAGS];
  #pragma unroll
  for (int i = 0; i < TAGS; ++i) Tc[i] = trans[i * TAGS + j];
  float alpha[TAGS];
  #pragma unroll
  for (int i = 0; i < TAGS; ++i) alpha[i] = lg[i];

  for (int t = 1; t < TT; ++t) {
    float m = -1e30f;
    #pragma unroll
    for (int i = 0; i < TAGS; ++i) m = fmaxf(m, alpha[i] + Tc[i]);
    float ssum = 0.f;
    #pragma unroll
    for (int i = 0; i < TAGS; ++i) ssum += __expf(alpha[i] + Tc[i] - m);
    float nj = m + __logf(ssum) + lg[t * TAGS + j];
    bool upd = (t < len);
    float na[TAGS];
    #pragma unroll
    for (int i = 0; i < TAGS; ++i) na[i] = __shfl(nj, i);
    if (upd)
      #pragma unroll
      for (int i = 0; i < TAGS; ++i) alpha[i] = na[i];
  }
  if (lane == 0) {
    float m = -1e30f;
    #pragma unroll
    for (int i = 0; i < TAGS; ++i) m = fmaxf(m, alpha[i]);
    float ssum = 0.f;
    #pragma unroll
    for (int i = 0; i < TAGS; ++i) ssum += __expf(alpha[i] - m);
    float ln = m + __logf(ssum);
    out[b] = (len > 0) ? (sc - ln) : 0.f;
  }
}

__global__ void k_copy_trans(const float* __restrict__ trans, float* __restrict__ out) {
  int i = threadIdx.x;
  if (i < TAGS * TAGS) out[BB + i] = trans[i];
}

extern "C" void kernel_launch(void* const* d_in, const int* in_sizes, int n_in,
                              void* d_out, int out_size, void* d_ws, size_t ws_size,
                              hipStream_t stream) {
  const int*   inp    = (const int*)d_in[0];
  const float* ch     = (const float*)d_in[1];
  const int*   labels = (const int*)d_in[2];
  const float* E      = (const float*)d_in[3];
  const float* Wx_f   = (const float*)d_in[4];
  const float* Wh_f   = (const float*)d_in[5];
  const float* b_f    = (const float*)d_in[6];
  const float* Wx_b   = (const float*)d_in[7];
  const float* Wh_b   = (const float*)d_in[8];
  const float* b_b    = (const float*)d_in[9];
  const float* Wd     = (const float*)d_in[10];
  const float* bd     = (const float*)d_in[11];
  const float* trans  = (const float*)d_in[12];
  float* out = (float*)d_out;

  // workspace layout (bytes): all 16B-aligned
  unsigned short* x    = (unsigned short*)d_ws;                 // B*T*128 bf16      (33.5 MB)
  unsigned short* hseq = x + (size_t)BB * TT * 128;             // 2*B*T*128 bf16    (67 MB)
  unsigned short* WxT  = hseq + (size_t)2 * BB * TT * 128;      // 2*512*128 bf16
  unsigned short* WhT  = WxT + 2 * NG * 128;                    // 2*512*128 bf16
  float* logits        = (float*)(WhT + 2 * NG * 128);          // B*T*9 f32         (4.7 MB)
  int*   lengths       = (int*)(logits + (size_t)BB * TT * TAGS);

  k_build_x<<<(BB * TT * 128) / 256, 256, 0, stream>>>(inp, ch, E, x);
  k_prep_w<<<(2 * NG * 128) / 256, 256, 0, stream>>>(Wx_f, Wh_f, Wx_b, Wh_b, WxT, WhT);
  k_lengths<<<BB, 64, 0, stream>>>(labels, lengths);
  k_lstm<<<32, 512, 0, stream>>>(x, WxT, WhT, b_f, b_b, hseq);
  k_logits<<<(BB * TT) / 256, 256, 0, stream>>>(hseq, Wd, bd, logits);
  k_crf<<<BB, 64, 0, stream>>>(logits, labels, lengths, trans, out);
  k_copy_trans<<<1, 128, 0, stream>>>(trans, out);
}

// Round 2
// 781.671 us; speedup vs baseline: 1.4559x; 1.4559x over previous
//
#include <hip/hip_runtime.h>

#define BB   256
#define TT   512
#define EMBD 64
#define CHARD 50
#define DIN  114
#define RNN  128
#define NG   512   // 4*RNN
#define TAGS 9
#define CH   4           // recurrence steps per chunk
#define NCHK (TT / CH)   // 128 chunks

typedef __bf16 bf16x8 __attribute__((ext_vector_type(8)));
typedef float  f32x4  __attribute__((ext_vector_type(4)));

static __device__ __forceinline__ unsigned short f2bf(float f) {
  unsigned int u = __float_as_uint(f);
  unsigned int r = (u + 0x7FFFu + ((u >> 16) & 1u)) >> 16;  // RNE
  return (unsigned short)r;
}
static __device__ __forceinline__ void gl_lds16(const void* g, void* l) {
  __builtin_amdgcn_global_load_lds(
      (const __attribute__((address_space(1))) unsigned int*)g,
      (__attribute__((address_space(3))) unsigned int*)l, 16, 0, 0);
}

// ---------------- x = concat(E[inputs], char_emb) padded to 128, bf16 ----------------
__global__ void k_build_x(const int* __restrict__ inp, const float* __restrict__ ch,
                          const float* __restrict__ E, unsigned short* __restrict__ x) {
  int idx = blockIdx.x * 256 + threadIdx.x;   // over B*T*128
  int k   = idx & 127;
  int row = idx >> 7;                          // b*T+t
  float v;
  if (k < EMBD)      v = E[inp[row] * EMBD + k];
  else if (k < DIN)  v = ch[row * CHARD + (k - EMBD)];
  else               v = 0.f;
  x[idx] = f2bf(v);
}

// ------------- transpose weights to [n][k] bf16 so B-fragments are contiguous -------------
__global__ void k_prep_w(const float* __restrict__ Wx_f, const float* __restrict__ Wh_f,
                         const float* __restrict__ Wx_b, const float* __restrict__ Wh_b,
                         unsigned short* __restrict__ WxT, unsigned short* __restrict__ WhT) {
  int idx = blockIdx.x * 256 + threadIdx.x;   // over 2*512*128
  int dir = idx >> 16;
  int rem = idx & 65535;
  int n   = rem >> 7;
  int kk  = rem & 127;
  const float* Wx = dir ? Wx_b : Wx_f;
  const float* Wh = dir ? Wh_b : Wh_f;
  WxT[idx] = (kk < DIN) ? f2bf(Wx[kk * NG + n]) : (unsigned short)0;
  WhT[idx] = f2bf(Wh[kk * NG + n]);
}

__global__ void k_lengths(const int* __restrict__ labels, int* __restrict__ lengths) {
  int b = blockIdx.x, lane = threadIdx.x;
  int cnt = 0;
  for (int t = lane; t < TT; t += 64) cnt += (labels[b * TT + t] != 0);
  for (int o = 32; o > 0; o >>= 1) cnt += __shfl_down(cnt, o);
  if (lane == 0) lengths[b] = cnt;
}

// ---------------- the sequential BiLSTM recurrence ----------------
// 32 WGs: wg<16 forward, wg>=16 backward; each WG owns 16 batch rows, 8 waves
// each owning a 16-wide hidden slice. All vmem at chunk boundaries only:
//  - x staged 1 chunk ahead via global_load_lds into fragment-layout LDS ring
//  - h kept in an 8-slot fragment-layout LDS ring; previous chunk stored to
//    global coalesced at each boundary (one vmcnt(0) per CH steps)
// Inner step: ds_read_b128 x/h frags -> 32 MFMA -> gates -> ds_write_b16 h ->
// lgkmcnt(0) + raw s_barrier (no vmcnt drain).
__global__ __launch_bounds__(512, 2) void k_lstm(
    const unsigned short* __restrict__ x,     // [B][T][128] bf16
    const unsigned short* __restrict__ WxT,   // [2][512][128] bf16
    const unsigned short* __restrict__ WhT,   // [2][512][128] bf16
    const float* __restrict__ b_f, const float* __restrict__ b_b,
    unsigned short* __restrict__ hseq)        // [2][B][T][128] bf16
{
  __shared__ __align__(16) unsigned short SH[32768];  // 64 KB total
  unsigned short* xr = SH;            // [2][CH][4kt][64 lane][8] = 16384 shorts
  unsigned short* hr = SH + 16384;    // [8 slot][4kt][64 lane][8] = 16384 shorts

  const int wg = blockIdx.x, dir = wg >> 4, b0 = (wg & 15) * 16;
  const int tid = threadIdx.x, w = tid >> 6, lane = tid & 63;
  const int lq = lane & 15, lg = lane >> 4;

  const unsigned short* WxD = WxT + dir * (NG * 128);
  const unsigned short* WhD = WhT + dir * (NG * 128);
  const float* bias = dir ? b_b : b_f;
  unsigned short* hout = hseq + (size_t)dir * ((size_t)BB * TT * 128);

  // weight B-fragments in registers: n = g*128 + w*16 + lq, k = kt*32 + lg*8
  bf16x8 wx[4][4], wh[4][4];
  float bs[4];
  #pragma unroll
  for (int g = 0; g < 4; ++g) {
    int n = g * RNN + w * 16 + lq;
    bs[g] = bias[n];
    #pragma unroll
    for (int kt = 0; kt < 4; ++kt) {
      wx[g][kt] = *reinterpret_cast<const bf16x8*>(WxD + n * 128 + kt * 32 + lg * 8);
      wh[g][kt] = *reinterpret_cast<const bf16x8*>(WhD + n * 128 + kt * 32 + lg * 8);
    }
  }

  // h-write mapping into fragment layout:
  //   element (row=lg*4+r, hid=w*16+lq) -> kt=w>>1, lane'=(lg*4+r)+16*q4, byte e=lq&7
  const int q4  = (2 * w + (lq >> 3)) & 3;
  const int hwb = (w >> 1) * 512 + (lg * 4 + 16 * q4) * 8 + (lq & 7);  // + r*8 + slot*2048

  // zero h slot 7 (initial hidden state; s=0 reads slot (0-1)&7 = 7)
  if (tid < 256) *reinterpret_cast<f32x4*>(&hr[7 * 2048 + tid * 8]) = f32x4{0.f, 0.f, 0.f, 0.f};

  // stage chunk 0 -> xbuf 0: wave w issues (sc,kt) pairs idx = 2w, 2w+1
  #pragma unroll
  for (int j = 0; j < 2; ++j) {
    int idx = w * 2 + j, sc = idx >> 2, kt = idx & 3;
    int t = dir ? (TT - 1 - sc) : sc;
    gl_lds16(x + ((size_t)(b0 + lq) * TT + t) * 128 + kt * 32 + lg * 8,
             xr + sc * 2048 + kt * 512);
  }
  asm volatile("s_waitcnt vmcnt(0) lgkmcnt(0)" ::: "memory");
  __builtin_amdgcn_s_barrier();

  f32x4 c = {0.f, 0.f, 0.f, 0.f};

  for (int cc = 0; cc < NCHK; ++cc) {
    const int sbase = cc * CH;
    const int slotb = (cc & 1) * CH;        // this chunk writes slots slotb..slotb+3
    const int xbuf  = (cc & 1) * 8192;

    // coalesced store of previous chunk's h (other slot half) — fire and forget
    if (cc > 0) {
      const int pb = ((cc - 1) & 1) * CH, ps = sbase - CH;
      #pragma unroll
      for (int j = 0; j < 2; ++j) {
        int u = tid + j * 512;
        int row = u >> 6, tc = (u >> 4) & 3, h16 = u & 15;
        int s = ps + tc, t = dir ? (TT - 1 - s) : s;
        bf16x8 v = *reinterpret_cast<const bf16x8*>(
            &hr[(pb + tc) * 2048 + (h16 >> 2) * 512 + (row + 16 * (h16 & 3)) * 8]);
        *reinterpret_cast<bf16x8*>(&hout[((size_t)(b0 + row) * TT + t) * 128 + h16 * 8]) = v;
      }
    }
    // stage next chunk's x into the other buffer (latency hides under CH steps)
    if (cc + 1 < NCHK) {
      #pragma unroll
      for (int j = 0; j < 2; ++j) {
        int idx = w * 2 + j, sc = idx >> 2, kt = idx & 3;
        int s = sbase + CH + sc, t = dir ? (TT - 1 - s) : s;
        gl_lds16(x + ((size_t)(b0 + lq) * TT + t) * 128 + kt * 32 + lg * 8,
                 xr + (((cc + 1) & 1) * 8192) + sc * 2048 + kt * 512);
      }
    }

    #pragma unroll
    for (int sc = 0; sc < CH; ++sc) {
      const unsigned short* xb = xr + xbuf + sc * 2048 + lane * 8;
      const unsigned short* hb = hr + (((slotb + sc - 1) & 7) * 2048) + lane * 8;
      bf16x8 xf[4], hf[4];
      #pragma unroll
      for (int kt = 0; kt < 4; ++kt) {
        xf[kt] = *reinterpret_cast<const bf16x8*>(xb + kt * 512);
        hf[kt] = *reinterpret_cast<const bf16x8*>(hb + kt * 512);
      }
      f32x4 acc[4];
      #pragma unroll
      for (int g = 0; g < 4; ++g) acc[g] = f32x4{bs[g], bs[g], bs[g], bs[g]};
      #pragma unroll
      for (int kt = 0; kt < 4; ++kt)
        #pragma unroll
        for (int g = 0; g < 4; ++g) {
          acc[g] = __builtin_amdgcn_mfma_f32_16x16x32_bf16(xf[kt], wx[g][kt], acc[g], 0, 0, 0);
          acc[g] = __builtin_amdgcn_mfma_f32_16x16x32_bf16(hf[kt], wh[g][kt], acc[g], 0, 0, 0);
        }
      unsigned short* hw = hr + (slotb + sc) * 2048 + hwb;
      #pragma unroll
      for (int r = 0; r < 4; ++r) {
        float zi = acc[0][r], zf = acc[1][r], zg = acc[2][r], zo = acc[3][r];
        float si = __builtin_amdgcn_rcpf(1.f + __expf(-zi));
        float sf = __builtin_amdgcn_rcpf(1.f + __expf(-zf));
        float so = __builtin_amdgcn_rcpf(1.f + __expf(-zo));
        float tg = 1.f - 2.f * __builtin_amdgcn_rcpf(__expf(2.f * zg) + 1.f);
        float cn = sf * c[r] + si * tg;
        float th = 1.f - 2.f * __builtin_amdgcn_rcpf(__expf(2.f * cn) + 1.f);
        c[r] = cn;
        hw[r * 8] = f2bf(so * th);
      }
      asm volatile("s_waitcnt lgkmcnt(0)" ::: "memory");
      if (sc == CH - 1) asm volatile("s_waitcnt vmcnt(0)" ::: "memory");
      __builtin_amdgcn_s_barrier();
    }
  }

  // store final chunk
  {
    const int pb = ((NCHK - 1) & 1) * CH, ps = (NCHK - 1) * CH;
    #pragma unroll
    for (int j = 0; j < 2; ++j) {
      int u = tid + j * 512;
      int row = u >> 6, tc = (u >> 4) & 3, h16 = u & 15;
      int s = ps + tc, t = dir ? (TT - 1 - s) : s;
      bf16x8 v = *reinterpret_cast<const bf16x8*>(
          &hr[(pb + tc) * 2048 + (h16 >> 2) * 512 + (row + 16 * (h16 & 3)) * 8]);
      *reinterpret_cast<bf16x8*>(&hout[((size_t)(b0 + row) * TT + t) * 128 + h16 * 8]) = v;
    }
  }
}

// ---------------- logits = [h_f, h_b] @ Wd + bd ----------------
__global__ void k_logits(const unsigned short* __restrict__ hseq,
                         const float* __restrict__ Wd, const float* __restrict__ bd,
                         float* __restrict__ logits) {
  __shared__ __align__(16) float sW[2 * RNN * 12];  // rows padded 9->12 for float4 loads
  __shared__ float sb[TAGS];
  int tid = threadIdx.x;
  for (int i = tid; i < 2 * RNN * TAGS; i += 256) {
    int k = i / TAGS, j = i - k * TAGS;
    sW[k * 12 + j] = Wd[i];
  }
  if (tid < TAGS) sb[tid] = bd[tid];
  __syncthreads();

  int bt = blockIdx.x * 256 + tid;   // b*T + t
  float a[TAGS];
  #pragma unroll
  for (int j = 0; j < TAGS; ++j) a[j] = sb[j];

  const unsigned short* hp[2];
  hp[0] = hseq + (size_t)bt * 128;
  hp[1] = hseq + (size_t)BB * TT * 128 + (size_t)bt * 128;
  #pragma unroll
  for (int d = 0; d < 2; ++d) {
    #pragma unroll
    for (int kv = 0; kv < RNN / 8; ++kv) {
      bf16x8 v = *reinterpret_cast<const bf16x8*>(hp[d] + kv * 8);
      #pragma unroll
      for (int e = 0; e < 8; ++e) {
        float f = (float)v[e];
        int k = d * RNN + kv * 8 + e;
        const float4* wrow = reinterpret_cast<const float4*>(sW + k * 12);
        float4 wa = wrow[0], wb = wrow[1];
        float  wc = sW[k * 12 + 8];
        a[0] += f * wa.x; a[1] += f * wa.y; a[2] += f * wa.z; a[3] += f * wa.w;
        a[4] += f * wb.x; a[5] += f * wb.y; a[6] += f * wb.z; a[7] += f * wb.w;
        a[8] += f * wc;
      }
    }
  }
  #pragma unroll
  for (int j = 0; j < TAGS; ++j) logits[(size_t)bt * TAGS + j] = a[j];
}

// ---------------- CRF log-likelihood; one wave per batch row ----------------
__global__ void k_crf(const float* __restrict__ logits, const int* __restrict__ labels,
                      const int* __restrict__ lengths, const float* __restrict__ trans,
                      float* __restrict__ out) {
  int b = blockIdx.x;
  int lane = threadIdx.x;
  int len = lengths[b];
  const float* lg = logits + (size_t)b * TT * TAGS;
  const int*   lab = labels + b * TT;

  // unary + binary scores, lane-parallel over t
  float sc = 0.f;
  for (int t = lane; t < TT; t += 64) {
    if (t < len) {
      sc += lg[t * TAGS + lab[t]];
      if (t >= 1) sc += trans[lab[t - 1] * TAGS + lab[t]];
    }
  }
  for (int o = 32; o > 0; o >>= 1) sc += __shfl_down(sc, o);
  sc = __shfl(sc, 0);

  // forward algorithm: lane j owns tag j; alpha replicated across lanes
  int j = (lane < TAGS) ? lane : 0;
  float Tc[TAGS];
  #pragma unroll
  for (int i = 0; i < TAGS; ++i) Tc[i] = trans[i * TAGS + j];
  float alpha[TAGS];
  #pragma unroll
  for (int i = 0; i < TAGS; ++i) alpha[i] = lg[i];

  for (int t = 1; t < TT; ++t) {
    float m = -1e30f;
    #pragma unroll
    for (int i = 0; i < TAGS; ++i) m = fmaxf(m, alpha[i] + Tc[i]);
    float ssum = 0.f;
    #pragma unroll
    for (int i = 0; i < TAGS; ++i) ssum += __expf(alpha[i] + Tc[i] - m);
    float nj = m + __logf(ssum) + lg[t * TAGS + j];
    bool upd = (t < len);
    float na[TAGS];
    #pragma unroll
    for (int i = 0; i < TAGS; ++i) na[i] = __shfl(nj, i);
    if (upd)
      #pragma unroll
      for (int i = 0; i < TAGS; ++i) alpha[i] = na[i];
  }
  if (lane == 0) {
    float m = -1e30f;
    #pragma unroll
    for (int i = 0; i < TAGS; ++i) m = fmaxf(m, alpha[i]);
    float ssum = 0.f;
    #pragma unroll
    for (int i = 0; i < TAGS; ++i) ssum += __expf(alpha[i] - m);
    float ln = m + __logf(ssum);
    out[b] = (len > 0) ? (sc - ln) : 0.f;
  }
}

__global__ void k_copy_trans(const float* __restrict__ trans, float* __restrict__ out) {
  int i = threadIdx.x;
  if (i < TAGS * TAGS) out[BB + i] = trans[i];
}

extern "C" void kernel_launch(void* const* d_in, const int* in_sizes, int n_in,
                              void* d_out, int out_size, void* d_ws, size_t ws_size,
                              hipStream_t stream) {
  const int*   inp    = (const int*)d_in[0];
  const float* ch     = (const float*)d_in[1];
  const int*   labels = (const int*)d_in[2];
  const float* E      = (const float*)d_in[3];
  const float* Wx_f   = (const float*)d_in[4];
  const float* Wh_f   = (const float*)d_in[5];
  const float* b_f    = (const float*)d_in[6];
  const float* Wx_b   = (const float*)d_in[7];
  const float* Wh_b   = (const float*)d_in[8];
  const float* b_b    = (const float*)d_in[9];
  const float* Wd     = (const float*)d_in[10];
  const float* bd     = (const float*)d_in[11];
  const float* trans  = (const float*)d_in[12];
  float* out = (float*)d_out;

  // workspace layout: all 16B-aligned
  unsigned short* x    = (unsigned short*)d_ws;                 // B*T*128 bf16
  unsigned short* hseq = x + (size_t)BB * TT * 128;             // 2*B*T*128 bf16
  unsigned short* WxT  = hseq + (size_t)2 * BB * TT * 128;      // 2*512*128 bf16
  unsigned short* WhT  = WxT + 2 * NG * 128;                    // 2*512*128 bf16
  float* logits        = (float*)(WhT + 2 * NG * 128);          // B*T*9 f32
  int*   lengths       = (int*)(logits + (size_t)BB * TT * TAGS);

  k_build_x<<<(BB * TT * 128) / 256, 256, 0, stream>>>(inp, ch, E, x);
  k_prep_w<<<(2 * NG * 128) / 256, 256, 0, stream>>>(Wx_f, Wh_f, Wx_b, Wh_b, WxT, WhT);
  k_lengths<<<BB, 64, 0, stream>>>(labels, lengths);
  k_lstm<<<32, 512, 0, stream>>>(x, WxT, WhT, b_f, b_b, hseq);
  k_logits<<<(BB * TT) / 256, 256, 0, stream>>>(hseq, Wd, bd, logits);
  k_crf<<<BB, 64, 0, stream>>>(logits, labels, lengths, trans, out);
  k_copy_trans<<<1, 128, 0, stream>>>(trans, out);
}

// Round 3
// 748.158 us; speedup vs baseline: 1.5212x; 1.0448x over previous
//
#include <hip/hip_runtime.h>

#define BB   256
#define TT   512
#define EMBD 64
#define CHARD 50
#define DIN  114
#define RNN  128
#define NG   512   // 4*RNN
#define TAGS 9

typedef __bf16 bf16x8 __attribute__((ext_vector_type(8)));
typedef float  f32x4  __attribute__((ext_vector_type(4)));
typedef unsigned int uint4v __attribute__((ext_vector_type(4)));
union U8 { bf16x8 v; uint4v u; };

static __device__ __forceinline__ unsigned short f2bf(float f) {
  unsigned int u = __float_as_uint(f);
  unsigned int r = (u + 0x7FFFu + ((u >> 16) & 1u)) >> 16;  // RNE
  return (unsigned short)r;
}
static __device__ __forceinline__ void gl_lds16(const void* g, void* l) {
  __builtin_amdgcn_global_load_lds(
      (const __attribute__((address_space(1))) unsigned int*)g,
      (__attribute__((address_space(3))) unsigned int*)l, 16, 0, 0);
}
// LDS 16B-unit swizzle (involution; spreads 16-unit-strided access over banks)
static __device__ __forceinline__ int swz(int u) { return u ^ ((u >> 4) & 7); }

// ---------------- x = concat(E[inputs], char_emb) padded to 128, bf16 ----------------
__global__ void k_build_x(const int* __restrict__ inp, const float* __restrict__ ch,
                          const float* __restrict__ E, unsigned short* __restrict__ x) {
  int idx = blockIdx.x * 256 + threadIdx.x;   // over B*T*128
  int k   = idx & 127;
  int row = idx >> 7;                          // b*T+t
  float v;
  if (k < EMBD)      v = E[inp[row] * EMBD + k];
  else if (k < DIN)  v = ch[row * CHARD + (k - EMBD)];
  else               v = 0.f;
  x[idx] = f2bf(v);
}

// ------- weights -> [n][k] bf16 (B-frag friendly); block 512 builds WdT [16][256] -------
__global__ void k_prep_w(const float* __restrict__ Wx_f, const float* __restrict__ Wh_f,
                         const float* __restrict__ Wx_b, const float* __restrict__ Wh_b,
                         const float* __restrict__ Wd,
                         unsigned short* __restrict__ WxT, unsigned short* __restrict__ WhT,
                         unsigned short* __restrict__ WdT) {
  if (blockIdx.x == 512) {
    for (int i = threadIdx.x; i < 16 * 256; i += 256) {
      int n = i >> 8, k = i & 255;
      WdT[i] = (n < TAGS) ? f2bf(Wd[k * TAGS + n]) : (unsigned short)0;
    }
    return;
  }
  int idx = blockIdx.x * 256 + threadIdx.x;   // over 2*512*128
  int dir = idx >> 16;
  int rem = idx & 65535;
  int n   = rem >> 7;
  int kk  = rem & 127;
  const float* Wx = dir ? Wx_b : Wx_f;
  const float* Wh = dir ? Wh_b : Wh_f;
  WxT[idx] = (kk < DIN) ? f2bf(Wx[kk * NG + n]) : (unsigned short)0;
  WhT[idx] = f2bf(Wh[kk * NG + n]);
}

__global__ void k_lengths(const int* __restrict__ labels, int* __restrict__ lengths) {
  int b = blockIdx.x, lane = threadIdx.x;
  int cnt = 0;
  for (int t = lane; t < TT; t += 64) cnt += (labels[b * TT + t] != 0);
  for (int o = 32; o > 0; o >>= 1) cnt += __shfl_down(cnt, o);
  if (lane == 0) lengths[b] = cnt;
}

// ---------------- z = x @ Wx + b for an s-range, all 256 CUs ----------------
// z layout: [s-s0][dir][bg][w][lane][16 bf16] -- exact k_lstm fragment order.
__global__ __launch_bounds__(512, 2) void k_zgemm(
    const unsigned short* __restrict__ x, const unsigned short* __restrict__ WxT,
    const float* __restrict__ b_f, const float* __restrict__ b_b,
    unsigned short* __restrict__ zbuf, int s0, int TCH) {
  __shared__ __align__(16) unsigned short xr[16384];  // 2 buf x 4 sc x 2048

  const int bid = blockIdx.x;
  const int dir = bid / (16 * TCH);
  const int rem = bid % (16 * TCH);
  const int bg  = rem / TCH, tch = rem % TCH;
  const int b0  = bg * 16;
  const int sb  = s0 + tch * 16;

  const int tid = threadIdx.x, w = tid >> 6, l = tid & 63;
  const int lq = l & 15, lg = l >> 4;

  const unsigned short* WxD = WxT + dir * (NG * 128);
  const float* bias = dir ? b_b : b_f;

  bf16x8 wx[4][4];
  float bs[4];
  #pragma unroll
  for (int g = 0; g < 4; ++g) {
    int n = g * RNN + w * 16 + lq;
    bs[g] = bias[n];
    #pragma unroll
    for (int kt = 0; kt < 4; ++kt)
      wx[g][kt] = *reinterpret_cast<const bf16x8*>(WxD + n * 128 + kt * 32 + lg * 8);
  }

  // stage chunk ci (4 timesteps) into buffer ci&1
  auto stage = [&](int ci) {
    int buf = ci & 1;
    #pragma unroll
    for (int j = 0; j < 2; ++j) {
      int idx = w * 2 + j, sc = idx >> 2, kt = idx & 3;
      int s = sb + ci * 4 + sc;
      int t = dir ? (TT - 1 - s) : s;
      gl_lds16(x + ((size_t)(b0 + lq) * TT + t) * 128 + kt * 32 + lg * 8,
               xr + buf * 8192 + sc * 2048 + kt * 512);
    }
  };

  stage(0);
  for (int ci = 0; ci < 4; ++ci) {
    asm volatile("s_waitcnt vmcnt(0) lgkmcnt(0)" ::: "memory");
    __builtin_amdgcn_s_barrier();
    if (ci < 3) stage(ci + 1);
    int buf = ci & 1;
    #pragma unroll
    for (int sc = 0; sc < 4; ++sc) {
      int s = sb + ci * 4 + sc;
      bf16x8 xf[4];
      #pragma unroll
      for (int kt = 0; kt < 4; ++kt)
        xf[kt] = *reinterpret_cast<const bf16x8*>(xr + buf * 8192 + sc * 2048 + kt * 512 + l * 8);
      f32x4 acc[4];
      #pragma unroll
      for (int g = 0; g < 4; ++g) acc[g] = f32x4{bs[g], bs[g], bs[g], bs[g]};
      #pragma unroll
      for (int kt = 0; kt < 4; ++kt)
        #pragma unroll
        for (int g = 0; g < 4; ++g)
          acc[g] = __builtin_amdgcn_mfma_f32_16x16x32_bf16(xf[kt], wx[g][kt], acc[g], 0, 0, 0);
      U8 zlo, zhi;
      #pragma unroll
      for (int g = 0; g < 2; ++g)
        #pragma unroll
        for (int r = 0; r < 4; ++r) {
          zlo.v[g * 4 + r] = (__bf16)acc[g][r];
          zhi.v[g * 4 + r] = (__bf16)acc[g + 2][r];
        }
      unsigned short* zp = zbuf + (size_t)(s - s0) * 262144 + dir * 131072 +
                           bg * 8192 + w * 1024 + l * 16;
      *reinterpret_cast<bf16x8*>(zp)     = zlo.v;
      *reinterpret_cast<bf16x8*>(zp + 8) = zhi.v;
    }
  }
}

// ---------------- BiLSTM recurrence, h@Wh only (z precomputed) ----------------
// 32 WGs; each owns 16 batch rows x 1 dir. Per step: 2 coalesced z loads (acc
// init), 4 swizzled ds_read_b128 h frags, 16 MFMA, gates, swizzled h write.
// LDS = 8-slot swizzled h ring (32KB). hout gather+store once per 4 steps.
__global__ __launch_bounds__(512, 2) void k_lstm(
    const unsigned short* __restrict__ zbuf, const unsigned short* __restrict__ WhT,
    unsigned short* __restrict__ hseq, float* __restrict__ cbuf,
    int s0, int s1, int first) {
  __shared__ __align__(16) unsigned short hr[16384];  // 8 slots x 2048 shorts (swizzled)

  const int wg = blockIdx.x, dir = wg >> 4, bg = wg & 15, b0 = bg * 16;
  const int tid = threadIdx.x, w = tid >> 6, l = tid & 63;
  const int lq = l & 15, lg = l >> 4;

  const unsigned short* WhD = WhT + dir * (NG * 128);
  unsigned short* hout = hseq + (size_t)dir * ((size_t)BB * TT * 128);
  char* hrb = reinterpret_cast<char*>(hr);

  bf16x8 wh[4][4];
  #pragma unroll
  for (int g = 0; g < 4; ++g) {
    int n = g * RNN + w * 16 + lq;
    #pragma unroll
    for (int kt = 0; kt < 4; ++kt)
      wh[g][kt] = *reinterpret_cast<const bf16x8*>(WhD + n * 128 + kt * 32 + lg * 8);
  }

  // swizzled h-frag read offsets (bytes within a slot)
  int ro[4];
  #pragma unroll
  for (int kt = 0; kt < 4; ++kt) ro[kt] = swz(kt * 64 + l) * 16;
  // swizzled h write offsets per r (bytes within a slot)
  int wo[4];
  #pragma unroll
  for (int r = 0; r < 4; ++r) {
    int u = (w >> 1) * 64 + ((w & 1) * 2 + (lq >> 3)) * 16 + lg * 4 + r;
    wo[r] = swz(u) * 16 + (lq & 7) * 2;
  }

  f32x4 c;
  if (first) {
    c = f32x4{0.f, 0.f, 0.f, 0.f};
    if (tid < 256) {  // zero slot 7 (initial h)
      int h16 = tid & 15, row = tid >> 4;
      int u = (h16 >> 2) * 64 + (h16 & 3) * 16 + row;
      *reinterpret_cast<f32x4*>(hrb + 7 * 4096 + swz(u) * 16) = f32x4{0.f, 0.f, 0.f, 0.f};
    }
  } else {
    #pragma unroll
    for (int r = 0; r < 4; ++r)
      c[r] = cbuf[(size_t)(dir * BB + b0 + lg * 4 + r) * RNN + w * 16 + lq];
    if (tid < 256) {  // load h(prev t) from hseq into slot 7 (swizzled)
      int h16 = tid & 15, row = tid >> 4;
      int tprev = dir ? (TT - s0) : (s0 - 1);
      bf16x8 v = *reinterpret_cast<const bf16x8*>(
          hout + ((size_t)(b0 + row) * TT + tprev) * 128 + h16 * 8);
      int u = (h16 >> 2) * 64 + (h16 & 3) * 16 + row;
      *reinterpret_cast<bf16x8*>(hrb + 7 * 4096 + swz(u) * 16) = v;
    }
  }
  __syncthreads();

  const unsigned short* zQ = zbuf + dir * 131072 + bg * 8192 + w * 1024 + l * 16;
  bf16x8 zAl = *reinterpret_cast<const bf16x8*>(zQ);
  bf16x8 zAh = *reinterpret_cast<const bf16x8*>(zQ + 8);
  bf16x8 zBl = *reinterpret_cast<const bf16x8*>(zQ + 262144);
  bf16x8 zBh = *reinterpret_cast<const bf16x8*>(zQ + 262144 + 8);

  // gather+store 4 steps of h (slots sp..sp+3) to hseq, coalesced
  auto gather = [&](int sp) {
    #pragma unroll
    for (int j = 0; j < 2; ++j) {
      int ut = tid + j * 512;
      int h16 = ut & 15, tc = (ut >> 4) & 3, row = ut >> 6;
      int s = sp + tc;
      int t = dir ? (TT - 1 - s) : s;
      int u = (h16 >> 2) * 64 + (h16 & 3) * 16 + row;
      bf16x8 v = *reinterpret_cast<const bf16x8*>(hrb + (s & 7) * 4096 + swz(u) * 16);
      *reinterpret_cast<bf16x8*>(hout + ((size_t)(b0 + row) * TT + t) * 128 + h16 * 8) = v;
    }
  };

  for (int s = s0; s < s1; ++s) {
    // acc init from z (bf16 -> f32 via bit ops)
    U8 ul, uh; ul.v = zAl; uh.v = zAh;
    f32x4 acc[4];
    acc[0] = f32x4{__uint_as_float(ul.u[0] << 16), __uint_as_float(ul.u[0] & 0xffff0000u),
                   __uint_as_float(ul.u[1] << 16), __uint_as_float(ul.u[1] & 0xffff0000u)};
    acc[1] = f32x4{__uint_as_float(ul.u[2] << 16), __uint_as_float(ul.u[2] & 0xffff0000u),
                   __uint_as_float(ul.u[3] << 16), __uint_as_float(ul.u[3] & 0xffff0000u)};
    acc[2] = f32x4{__uint_as_float(uh.u[0] << 16), __uint_as_float(uh.u[0] & 0xffff0000u),
                   __uint_as_float(uh.u[1] << 16), __uint_as_float(uh.u[1] & 0xffff0000u)};
    acc[3] = f32x4{__uint_as_float(uh.u[2] << 16), __uint_as_float(uh.u[2] & 0xffff0000u),
                   __uint_as_float(uh.u[3] << 16), __uint_as_float(uh.u[3] & 0xffff0000u)};
    zAl = zBl; zAh = zBh;
    int sn = s + 2; if (sn > s1 - 1) sn = s1 - 1;
    const unsigned short* zp = zQ + (size_t)(sn - s0) * 262144;
    zBl = *reinterpret_cast<const bf16x8*>(zp);
    zBh = *reinterpret_cast<const bf16x8*>(zp + 8);

    const char* hb = hrb + ((s - 1) & 7) * 4096;
    bf16x8 hf[4];
    #pragma unroll
    for (int kt = 0; kt < 4; ++kt)
      hf[kt] = *reinterpret_cast<const bf16x8*>(hb + ro[kt]);
    #pragma unroll
    for (int kt = 0; kt < 4; ++kt)
      #pragma unroll
      for (int g = 0; g < 4; ++g)
        acc[g] = __builtin_amdgcn_mfma_f32_16x16x32_bf16(hf[kt], wh[g][kt], acc[g], 0, 0, 0);

    if ((s & 3) == 0 && s > s0) gather(s - 4);

    char* hwslot = hrb + (s & 7) * 4096;
    #pragma unroll
    for (int r = 0; r < 4; ++r) {
      float zi = acc[0][r], zf = acc[1][r], zg = acc[2][r], zo = acc[3][r];
      float si = __builtin_amdgcn_rcpf(1.f + __expf(-zi));
      float sf = __builtin_amdgcn_rcpf(1.f + __expf(-zf));
      float so = __builtin_amdgcn_rcpf(1.f + __expf(-zo));
      float tg = 1.f - 2.f * __builtin_amdgcn_rcpf(__expf(2.f * zg) + 1.f);
      float cn = sf * c[r] + si * tg;
      float th = 1.f - 2.f * __builtin_amdgcn_rcpf(__expf(2.f * cn) + 1.f);
      c[r] = cn;
      *reinterpret_cast<unsigned short*>(hwslot + wo[r]) = f2bf(so * th);
    }
    asm volatile("s_waitcnt lgkmcnt(0)" ::: "memory");
    __builtin_amdgcn_s_barrier();
  }

  gather(s1 - 4);
  #pragma unroll
  for (int r = 0; r < 4; ++r)
    cbuf[(size_t)(dir * BB + b0 + lg * 4 + r) * RNN + w * 16 + lq] = c[r];
}

// ---------------- logits = [h_f, h_b] @ Wd + bd via MFMA ----------------
// LDS tile [64 rows][256 cols] bf16, XOR-swizzled (u ^= (u>>5)&7), staged with
// pre-swizzled-source global_load_lds; 8 MFMA per wave-tile of 16 rows.
__global__ __launch_bounds__(256) void k_logits(const unsigned short* __restrict__ hseq,
                                                const unsigned short* __restrict__ WdT,
                                                const float* __restrict__ bd,
                                                float* __restrict__ logits) {
  __shared__ __align__(16) unsigned short xt[2][16384];  // 2 x 32KB
  const int tid = threadIdx.x, wv = tid >> 6, l = tid & 63;
  const int lq = l & 15, lg = l >> 4;
  const size_t HS = (size_t)BB * TT * 128;

  bf16x8 wb[8];
  #pragma unroll
  for (int kt = 0; kt < 8; ++kt)
    wb[kt] = *reinterpret_cast<const bf16x8*>(WdT + lq * 256 + kt * 32 + lg * 8);
  float bdv = (lq < TAGS) ? bd[lq] : 0.f;

  auto stage = [&](int it, int buf) {
    int bt0 = blockIdx.x * 256 + it * 64;
    #pragma unroll
    for (int i = 0; i < 8; ++i) {
      int v = tid + i * 256;                 // lds unit
      int g = v ^ ((v >> 5) & 7);            // pre-swizzled source unit
      int row = g >> 5, cu = g & 31;
      const unsigned short* src = (cu < 16)
          ? hseq + (size_t)(bt0 + row) * 128 + cu * 8
          : hseq + HS + (size_t)(bt0 + row) * 128 + (cu - 16) * 8;
      gl_lds16(src, &xt[buf][(i * 256 + wv * 64) * 8]);
    }
  };

  stage(0, 0);
  for (int it = 0; it < 4; ++it) {
    asm volatile("s_waitcnt vmcnt(12)" ::: "memory");
    __builtin_amdgcn_s_barrier();
    if (it < 3) stage(it + 1, (it + 1) & 1);
    int buf = it & 1;
    int bt0 = blockIdx.x * 256 + it * 64;
    int r0 = wv * 16;
    bf16x8 af[8];
    #pragma unroll
    for (int kt = 0; kt < 8; ++kt) {
      int u = (r0 + lq) * 32 + kt * 4 + lg;
      af[kt] = *reinterpret_cast<const bf16x8*>(&xt[buf][(u ^ ((u >> 5) & 7)) * 8]);
    }
    f32x4 acc = f32x4{bdv, bdv, bdv, bdv};
    #pragma unroll
    for (int kt = 0; kt < 8; ++kt)
      acc = __builtin_amdgcn_mfma_f32_16x16x32_bf16(af[kt], wb[kt], acc, 0, 0, 0);
    if (lq < TAGS) {
      #pragma unroll
      for (int r = 0; r < 4; ++r)
        logits[(size_t)(bt0 + r0 + lg * 4 + r) * TAGS + lq] = acc[r];
    }
    asm volatile("s_waitcnt lgkmcnt(0)" ::: "memory");
  }
}

// ---------------- CRF log-likelihood; one wave per batch row ----------------
__global__ void k_crf(const float* __restrict__ logits, const int* __restrict__ labels,
                      const int* __restrict__ lengths, const float* __restrict__ trans,
                      float* __restrict__ out) {
  int b = blockIdx.x;
  int lane = threadIdx.x;
  int len = lengths[b];
  const float* lg = logits + (size_t)b * TT * TAGS;
  const int*   lab = labels + b * TT;

  float sc = 0.f;
  for (int t = lane; t < TT; t += 64) {
    if (t < len) {
      sc += lg[t * TAGS + lab[t]];
      if (t >= 1) sc += trans[lab[t - 1] * TAGS + lab[t]];
    }
  }
  for (int o = 32; o > 0; o >>= 1) sc += __shfl_down(sc, o);
  sc = __shfl(sc, 0);

  int j = (lane < TAGS) ? lane : 0;
  float Tc[TAGS];
  #pragma unroll
  for (int i = 0; i < TAGS; ++i) Tc[i] = trans[i * TAGS + j];
  float alpha[TAGS];
  #pragma unroll
  for (int i = 0; i < TAGS; ++i) alpha[i] = lg[i];

  float pre[8];
  #pragma unroll
  for (int k = 0; k < 8; ++k) pre[k] = (1 + k < TT) ? lg[(1 + k) * TAGS + j] : 0.f;

  for (int tb = 1; tb < TT; tb += 8) {
    #pragma unroll
    for (int u = 0; u < 8; ++u) {
      int t = tb + u;
      if (t < TT) {
        float m = -1e30f;
        #pragma unroll
        for (int i = 0; i < TAGS; ++i) m = fmaxf(m, alpha[i] + Tc[i]);
        float ssum = 0.f;
        #pragma unroll
        for (int i = 0; i < TAGS; ++i) ssum += __expf(alpha[i] + Tc[i] - m);
        float nj = m + __logf(ssum) + pre[u];
        int tf = t + 8;
        pre[u] = (tf < TT) ? lg[tf * TAGS + j] : 0.f;
        bool upd = (t < len);
        float na[TAGS];
        #pragma unroll
        for (int i = 0; i < TAGS; ++i) na[i] = __shfl(nj, i);
        if (upd)
          #pragma unroll
          for (int i = 0; i < TAGS; ++i) alpha[i] = na[i];
      }
    }
  }
  if (lane == 0) {
    float m = -1e30f;
    #pragma unroll
    for (int i = 0; i < TAGS; ++i) m = fmaxf(m, alpha[i]);
    float ssum = 0.f;
    #pragma unroll
    for (int i = 0; i < TAGS; ++i) ssum += __expf(alpha[i] - m);
    float ln = m + __logf(ssum);
    out[b] = (len > 0) ? (sc - ln) : 0.f;
  }
}

__global__ void k_copy_trans(const float* __restrict__ trans, float* __restrict__ out) {
  int i = threadIdx.x;
  if (i < TAGS * TAGS) out[BB + i] = trans[i];
}

extern "C" void kernel_launch(void* const* d_in, const int* in_sizes, int n_in,
                              void* d_out, int out_size, void* d_ws, size_t ws_size,
                              hipStream_t stream) {
  const int*   inp    = (const int*)d_in[0];
  const float* ch     = (const float*)d_in[1];
  const int*   labels = (const int*)d_in[2];
  const float* E      = (const float*)d_in[3];
  const float* Wx_f   = (const float*)d_in[4];
  const float* Wh_f   = (const float*)d_in[5];
  const float* b_f    = (const float*)d_in[6];
  const float* Wx_b   = (const float*)d_in[7];
  const float* Wh_b   = (const float*)d_in[8];
  const float* b_b    = (const float*)d_in[9];
  const float* Wd     = (const float*)d_in[10];
  const float* bd     = (const float*)d_in[11];
  const float* trans  = (const float*)d_in[12];
  float* out = (float*)d_out;

  // workspace layout (all 16B aligned)
  unsigned short* x    = (unsigned short*)d_ws;                 // B*T*128 bf16     33.55 MB
  unsigned short* hseq = x + (size_t)BB * TT * 128;             // 2*B*T*128 bf16   67.11 MB
  unsigned short* WxT  = hseq + (size_t)2 * BB * TT * 128;      // 0.26 MB
  unsigned short* WhT  = WxT + 2 * NG * 128;                    // 0.26 MB
  unsigned short* WdT  = WhT + 2 * NG * 128;                    // 8 KB
  float* logits        = (float*)(WdT + 16 * 256);              // B*T*9 f32        4.72 MB
  float* cbuf          = logits + (size_t)BB * TT * TAGS;       // 0.52 MB
  int*   lengths       = (int*)(cbuf + (size_t)2 * BB * RNN);   // 1 KB
  unsigned short* zbuf = (unsigned short*)(lengths + 256);      // L*0.5 MB

  const size_t fixed_b = 106439680ull;
  int NP = 32;
  const int cands[5] = {2, 4, 8, 16, 32};
  for (int i = 0; i < 5; ++i) {
    if (fixed_b + (size_t)(TT / cands[i]) * 524288ull <= ws_size) { NP = cands[i]; break; }
  }
  const int L = TT / NP;

  k_build_x<<<(BB * TT * 128) / 256, 256, 0, stream>>>(inp, ch, E, x);
  k_prep_w<<<513, 256, 0, stream>>>(Wx_f, Wh_f, Wx_b, Wh_b, Wd, WxT, WhT, WdT);
  k_lengths<<<BB, 64, 0, stream>>>(labels, lengths);
  for (int p = 0; p < NP; ++p) {
    int s0 = p * L;
    k_zgemm<<<2 * 16 * (L / 16), 512, 0, stream>>>(x, WxT, b_f, b_b, zbuf, s0, L / 16);
    k_lstm<<<32, 512, 0, stream>>>(zbuf, WhT, hseq, cbuf, s0, s0 + L, p == 0);
  }
  k_logits<<<(BB * TT) / 256, 256, 0, stream>>>(hseq, WdT, bd, logits);
  k_crf<<<BB, 64, 0, stream>>>(logits, labels, lengths, trans, out);
  k_copy_trans<<<1, 128, 0, stream>>>(trans, out);
}